// Round 3
// baseline (1400.106 us; speedup 1.0000x reference)
//
#include <hip/hip_runtime.h>

#define NUC 8.0e-4f   // MIU/(U*L) = 1e-6/(0.025*0.05)

struct KP {
  const float *W0,*b0,*W1,*b1,*W2,*b2,*W3,*b3,*W4,*b4,*W5,*b5,*W6,*b6;
  const float *bc1,*bc2,*bc3,*bc4,*bc5,*f1,*inp,*real;
  float *wsBC,*wsDA,*wsF;
};

__device__ __forceinline__ float ftanh(float a){
  float e = __expf(2.0f*a);
  return 1.0f - 2.0f/(e + 1.0f);   // safe at +/-inf
}

__device__ __forceinline__ float rl(float v, int srclane){
  return __int_as_float(__builtin_amdgcn_readlane(__float_as_int(v), srclane));
}

__device__ __forceinline__ float wred64(float v){
  #pragma unroll
  for (int off=32; off>0; off>>=1) v += __shfl_down(v, off, 64);
  return v;
}

struct SharedU {
  float  Wt[2][4][256];   // 8 KB double-buffered W K-tile
  float2 xpt[32];
  float  fin[8][20];
  float  red[8];
  float  redA[4], redB[4];
};

// ---------------- PDE body: 8 points/block, 5 coupled streams ----------------
// wave w: points 2w,2w+1; lane owns cols 4*lane..4*lane+3; X lives in registers,
// broadcast via v_readlane (k = 4*srclane + slot).
__device__ __forceinline__ void pde_body(const KP& P, SharedU& S, int bid){
  const int tid = threadIdx.x;
  const int g0  = bid * 8;
  if (tid < 8){ int g = g0 + tid; S.xpt[tid] = make_float2(P.f1[2*g], P.f1[2*g+1]); }
  __syncthreads();

  const int lane = tid & 63;
  const int c0   = lane * 4;
  const int p0   = (tid >> 6) * 2;

  float xr[2][5][4];   // [pt][stream][slot]: this lane's cols = next layer's k=4*lane+slot

  // ---- layer 0 ----
  {
    float4 w0 = *(const float4*)(P.W0 + c0);
    float4 w1 = *(const float4*)(P.W0 + 256 + c0);
    float4 b0 = *(const float4*)(P.b0 + c0);
    const float wz[4] = {w0.x,w0.y,w0.z,w0.w};
    const float wr[4] = {w1.x,w1.y,w1.z,w1.w};
    const float bb[4] = {b0.x,b0.y,b0.z,b0.w};
    #pragma unroll
    for (int pp=0;pp<2;++pp){
      float x0 = S.xpt[p0+pp].x, x1 = S.xpt[p0+pp].y;
      #pragma unroll
      for (int c=0;c<4;++c){
        float a = x0*wz[c] + x1*wr[c] + bb[c];
        float t = ftanh(a), s = 1.f - t*t, cc = -2.f*t*s;
        xr[pp][0][c]=t; xr[pp][1][c]=s*wz[c]; xr[pp][2][c]=s*wr[c];
        xr[pp][3][c]=cc*wz[c]*wz[c]; xr[pp][4][c]=cc*wr[c]*wr[c];
      }
    }
  }

  // ---- layers 1..5 ----
  const float* Wl[5] = {P.W1,P.W2,P.W3,P.W4,P.W5};
  const float* bl[5] = {P.b1,P.b2,P.b3,P.b4,P.b5};
  for (int l=0;l<5;++l){
    const float* Wg = Wl[l];
    float acc[2][5][4];
    #pragma unroll
    for (int pp=0;pp<2;++pp)
      #pragma unroll
      for (int s=0;s<5;++s)
        #pragma unroll
        for (int c=0;c<4;++c) acc[pp][s][c] = 0.f;

    float4 ra = ((const float4*)Wg)[tid];
    for (int kt=0; kt<64; ++kt){
      const int buf = kt & 1;
      ((float4*)(&S.Wt[buf][0][0]))[tid] = ra;
      if (kt < 63) ra = ((const float4*)(Wg + (kt+1)*1024))[tid];
      __syncthreads();
      #pragma unroll
      for (int kk=0;kk<4;++kk){
        float4 wv = *(const float4*)&S.Wt[buf][kk][c0];
        #pragma unroll
        for (int pp=0;pp<2;++pp)
          #pragma unroll
          for (int s=0;s<5;++s){
            float xs = rl(xr[pp][s][kk], kt);
            acc[pp][s][0] += xs*wv.x; acc[pp][s][1] += xs*wv.y;
            acc[pp][s][2] += xs*wv.z; acc[pp][s][3] += xs*wv.w;
          }
      }
    }
    float4 bvl = *(const float4*)(bl[l] + c0);
    const float bb[4] = {bvl.x,bvl.y,bvl.z,bvl.w};
    #pragma unroll
    for (int pp=0;pp<2;++pp)
      #pragma unroll
      for (int c=0;c<4;++c){
        float a   = acc[pp][0][c] + bb[c];
        float Dz  = acc[pp][1][c], Dr = acc[pp][2][c];
        float Dzz = acc[pp][3][c], Drr = acc[pp][4][c];
        float t = ftanh(a), s = 1.f - t*t, cc = -2.f*t*s;
        xr[pp][0][c]=t; xr[pp][1][c]=s*Dz; xr[pp][2][c]=s*Dr;
        xr[pp][3][c]=s*Dzz + cc*Dz*Dz; xr[pp][4][c]=s*Drr + cc*Dr*Dr;
      }
  }

  // ---- layer 6: per-lane partial dots over its 4 k's, then wave butterfly ----
  float4 b6v = *(const float4*)P.b6;
  float4 part[2][5];
  #pragma unroll
  for (int pp=0;pp<2;++pp)
    #pragma unroll
    for (int s=0;s<5;++s){
      float4 a4 = make_float4(0.f,0.f,0.f,0.f);
      #pragma unroll
      for (int slot=0;slot<4;++slot){
        float4 w6r = *(const float4*)(P.W6 + (c0+slot)*4);   // W6[k][0..3]
        float x = xr[pp][s][slot];
        a4.x += x*w6r.x; a4.y += x*w6r.y; a4.z += x*w6r.z; a4.w += x*w6r.w;
      }
      part[pp][s] = a4;
    }
  #pragma unroll
  for (int pp=0;pp<2;++pp)
    #pragma unroll
    for (int s=0;s<5;++s){
      float4 v = part[pp][s];
      #pragma unroll
      for (int off=32; off>0; off>>=1){
        v.x += __shfl_xor(v.x, off, 64);
        v.y += __shfl_xor(v.y, off, 64);
        v.z += __shfl_xor(v.z, off, 64);
        v.w += __shfl_xor(v.w, off, 64);
      }
      part[pp][s] = v;
    }
  if (lane == 0){
    #pragma unroll
    for (int pp=0;pp<2;++pp)
      #pragma unroll
      for (int s=0;s<5;++s){
        float4 v = part[pp][s];
        if (s==0){ v.x+=b6v.x; v.y+=b6v.y; v.z+=b6v.z; v.w+=b6v.w; }
        *(float4*)&S.fin[p0+pp][4*s] = v;
      }
  }
  __syncthreads();
  if (tid < 8){
    const float* F = S.fin[tid];
    float r = S.xpt[tid].y;
    float uz=F[0],  us=F[1],  ur=F[2];
    float uz_z=F[4],us_z=F[5],ur_z=F[6],p_z=F[7];
    float uz_r=F[8],us_r=F[9],ur_r=F[10],p_r=F[11];
    float uz_zz=F[12],us_zz=F[13],ur_zz=F[14];
    float uz_rr=F[16],us_rr=F[17],ur_rr=F[18];
    float invr = 1.f/r;
    float eq1 = ur*ur_r + uz*ur_z - us*us*invr + p_r
              - NUC*invr*ur_r - NUC*ur_rr - NUC*ur_zz + NUC*ur*invr*invr;
    float eq2 = ur*us_r + uz*us_z + ur*us*invr
              - NUC*invr*us_r - NUC*us_rr - NUC*us_zz + NUC*us*invr*invr;
    float eq3 = ur*uz_r + uz*uz_z + p_z
              - NUC*invr*uz_r - NUC*uz_rr - NUC*uz_zz;
    float eq4 = ur + r*ur_r + r*uz_z;
    S.red[tid] = (eq1*eq1 + eq2*eq2 + eq3*eq3 + eq4*eq4) * (1.0f/80000.f);
  }
  __syncthreads();
  if (tid == 0){
    float sum = 0.f;
    #pragma unroll
    for (int i=0;i<8;++i) sum += S.red[i];
    P.wsF[bid] = sum;
  }
}

// ---------------- forward-only body: 32 points/block ----------------
// wave w: points w*8..w*8+7; lane owns cols 4*lane..4*lane+3.
__device__ __forceinline__ void fwd_body(const KP& P, SharedU& S, int bid){
  const int tid = threadIdx.x;
  const int g0  = bid * 32;
  if (tid < 32){
    int g = g0 + tid;
    float2 xy = make_float2(0.f,0.f);
    if (g < 37000){
      const float* src; int li;
      if      (g <  1000){ src=P.bc1; li=g; }
      else if (g <  2000){ src=P.bc2; li=g-1000; }
      else if (g <  7000){ src=P.bc3; li=g-2000; }
      else if (g < 12000){ src=P.bc4; li=g-7000; }
      else if (g < 17000){ src=P.bc5; li=g-12000; }
      else               { src=P.inp; li=g-17000; }
      xy.x = src[2*li]; xy.y = src[2*li+1];
    }
    S.xpt[tid] = xy;
  }
  __syncthreads();

  const int lane = tid & 63;
  const int c0   = lane * 4;
  const int p0   = (tid >> 6) * 8;

  float xr[8][4];
  {
    float4 w0 = *(const float4*)(P.W0 + c0);
    float4 w1 = *(const float4*)(P.W0 + 256 + c0);
    float4 b0 = *(const float4*)(P.b0 + c0);
    const float wz[4] = {w0.x,w0.y,w0.z,w0.w};
    const float wr[4] = {w1.x,w1.y,w1.z,w1.w};
    const float bb[4] = {b0.x,b0.y,b0.z,b0.w};
    #pragma unroll
    for (int i=0;i<8;++i){
      float x0 = S.xpt[p0+i].x, x1 = S.xpt[p0+i].y;
      #pragma unroll
      for (int c=0;c<4;++c)
        xr[i][c] = ftanh(x0*wz[c] + x1*wr[c] + bb[c]);
    }
  }

  const float* Wl[5] = {P.W1,P.W2,P.W3,P.W4,P.W5};
  const float* bl[5] = {P.b1,P.b2,P.b3,P.b4,P.b5};
  for (int l=0;l<5;++l){
    const float* Wg = Wl[l];
    float acc[8][4];
    #pragma unroll
    for (int i=0;i<8;++i){ acc[i][0]=0.f; acc[i][1]=0.f; acc[i][2]=0.f; acc[i][3]=0.f; }

    float4 ra = ((const float4*)Wg)[tid];
    for (int kt=0; kt<64; ++kt){
      const int buf = kt & 1;
      ((float4*)(&S.Wt[buf][0][0]))[tid] = ra;
      if (kt < 63) ra = ((const float4*)(Wg + (kt+1)*1024))[tid];
      __syncthreads();
      #pragma unroll
      for (int kk=0;kk<4;++kk){
        float4 wv = *(const float4*)&S.Wt[buf][kk][c0];
        #pragma unroll
        for (int i=0;i<8;++i){
          float xs = rl(xr[i][kk], kt);
          acc[i][0] += xs*wv.x; acc[i][1] += xs*wv.y;
          acc[i][2] += xs*wv.z; acc[i][3] += xs*wv.w;
        }
      }
    }
    float4 bvl = *(const float4*)(bl[l] + c0);
    const float bb[4] = {bvl.x,bvl.y,bvl.z,bvl.w};
    #pragma unroll
    for (int i=0;i<8;++i)
      #pragma unroll
      for (int c=0;c<4;++c)
        xr[i][c] = ftanh(acc[i][c] + bb[c]);
  }

  // ---- layer 6 + per-point MSE ----
  float4 b6v = *(const float4*)P.b6;
  float4 part[8];
  #pragma unroll
  for (int i=0;i<8;++i){
    float4 a4 = make_float4(0.f,0.f,0.f,0.f);
    #pragma unroll
    for (int slot=0;slot<4;++slot){
      float4 w6r = *(const float4*)(P.W6 + (c0+slot)*4);
      float x = xr[i][slot];
      a4.x += x*w6r.x; a4.y += x*w6r.y; a4.z += x*w6r.z; a4.w += x*w6r.w;
    }
    part[i] = a4;
  }
  #pragma unroll
  for (int i=0;i<8;++i){
    float4 v = part[i];
    #pragma unroll
    for (int off=32; off>0; off>>=1){
      v.x += __shfl_xor(v.x, off, 64);
      v.y += __shfl_xor(v.y, off, 64);
      v.z += __shfl_xor(v.z, off, 64);
      v.w += __shfl_xor(v.w, off, 64);
    }
    part[i] = v;
  }
  float bcp = 0.f, dap = 0.f;
  #pragma unroll
  for (int i=0;i<8;++i){          // static index; lane i handles point p0+i
    if (lane == i){
      float dj0 = part[i].x + b6v.x, dj1 = part[i].y + b6v.y;
      float dj2 = part[i].z + b6v.z, dj3 = part[i].w + b6v.w;
      int g = g0 + p0 + i;
      if (g < 37000){
        if      (g <  2000){ bcp = (dj0*dj0 + dj1*dj1 + dj2*dj2)*(1.0f/1000.f); }
        else if (g <  7000){ float d1 = dj1 - 1.f;
                             bcp = (dj0*dj0 + d1*d1 + dj2*dj2)*(1.0f/5000.f); }
        else if (g < 12000){ bcp = (dj0*dj0 + dj1*dj1 + dj2*dj2)*(1.0f/5000.f); }
        else if (g < 17000){ bcp = dj3*dj3*(1.0f/5000.f); }
        else { const float* rr = P.real + (g-17000)*4;
               float e0=dj0-rr[0], e1=dj1-rr[1], e2=dj2-rr[2], e3=dj3-rr[3];
               dap = (e0*e0 + e1*e1 + e2*e2 + e3*e3)*(1.0f/80000.f); }
      }
    }
  }
  bcp = wred64(bcp); dap = wred64(dap);
  if ((tid & 63) == 0){ S.redA[tid>>6] = bcp; S.redB[tid>>6] = dap; }
  __syncthreads();
  if (tid == 0){
    float sA=0.f, sB=0.f;
    #pragma unroll
    for (int w=0;w<4;++w){ sA += S.redA[w]; sB += S.redB[w]; }
    P.wsBC[bid] = sA; P.wsDA[bid] = sB;
  }
}

// ---------------- fused kernel: pde blocks first (longer), then fwd ----------------
__global__ __launch_bounds__(256,4) void fused_kernel(KP P, int nbP){
  __shared__ SharedU S;
  if ((int)blockIdx.x < nbP) pde_body(P, S, blockIdx.x);
  else                       fwd_body(P, S, blockIdx.x - nbP);
}

// ---------------- final deterministic reduction ----------------
__global__ void reduce_kernel(const float* wsBC, const float* wsDA, const float* wsF,
                              float* out, int nbF, int nbP){
  __shared__ float sm[256];
  const int tid = threadIdx.x;
  float a;

  a = 0.f; for (int i=tid;i<nbF;i+=256) a += wsBC[i];
  sm[tid]=a; __syncthreads();
  for (int off=128; off>0; off>>=1){ if (tid<off) sm[tid]+=sm[tid+off]; __syncthreads(); }
  if (tid==0) out[0]=sm[0];
  __syncthreads();

  a = 0.f; for (int i=tid;i<nbF;i+=256) a += wsDA[i];
  sm[tid]=a; __syncthreads();
  for (int off=128; off>0; off>>=1){ if (tid<off) sm[tid]+=sm[tid+off]; __syncthreads(); }
  if (tid==0) out[1]=sm[0];
  __syncthreads();

  a = 0.f; for (int i=tid;i<nbP;i+=256) a += wsF[i];
  sm[tid]=a; __syncthreads();
  for (int off=128; off>0; off>>=1){ if (tid<off) sm[tid]+=sm[tid+off]; __syncthreads(); }
  if (tid==0) out[2]=sm[0];
}

extern "C" void kernel_launch(void* const* d_in, const int* in_sizes, int n_in,
                              void* d_out, int out_size, void* d_ws, size_t ws_size,
                              hipStream_t stream){
  KP P;
  P.W0=(const float*)d_in[0];  P.b0=(const float*)d_in[1];
  P.W1=(const float*)d_in[2];  P.b1=(const float*)d_in[3];
  P.W2=(const float*)d_in[4];  P.b2=(const float*)d_in[5];
  P.W3=(const float*)d_in[6];  P.b3=(const float*)d_in[7];
  P.W4=(const float*)d_in[8];  P.b4=(const float*)d_in[9];
  P.W5=(const float*)d_in[10]; P.b5=(const float*)d_in[11];
  P.W6=(const float*)d_in[12]; P.b6=(const float*)d_in[13];
  P.bc1=(const float*)d_in[14]; P.bc2=(const float*)d_in[15];
  P.bc3=(const float*)d_in[16]; P.bc4=(const float*)d_in[17];
  P.bc5=(const float*)d_in[18]; P.f1=(const float*)d_in[19];
  P.inp=(const float*)d_in[20]; P.real=(const float*)d_in[21];
  float* ws = (float*)d_ws;
  P.wsBC = ws; P.wsDA = ws + 2048; P.wsF = ws + 4096;

  const int nbF = (37000 + 31) / 32;   // 1157
  const int nbP = 20000 / 8;           // 2500
  fused_kernel<<<dim3(nbP + nbF), dim3(256), 0, stream>>>(P, nbP);
  reduce_kernel<<<dim3(1), dim3(256), 0, stream>>>(P.wsBC, P.wsDA, P.wsF, (float*)d_out, nbF, nbP);
}

// Round 4
// 1365.223 us; speedup vs baseline: 1.0256x; 1.0256x over previous
//
#include <hip/hip_runtime.h>

#define NUC 8.0e-4f   // MIU/(U*L) = 1e-6/(0.025*0.05)

struct KP {
  const float *W0,*b0,*W1,*b1,*W2,*b2,*W3,*b3,*W4,*b4,*W5,*b5,*W6,*b6;
  const float *bc1,*bc2,*bc3,*bc4,*bc5,*f1,*inp,*real;
  float *wsBC,*wsDA,*wsF;
};

__device__ __forceinline__ float ftanh(float a){
  float e = __expf(2.0f*a);
  return 1.0f - 2.0f/(e + 1.0f);   // safe at +/-inf
}

__device__ __forceinline__ float rl(float v, int srclane){
  return __int_as_float(__builtin_amdgcn_readlane(__float_as_int(v), srclane));
}

struct MainS { float  Wt[2][8][256]; };   // 16 KB double-buffered W K-tile (KT=8)
struct EpiP  { float4 part[8][5][64]; };  // 40 KB pde layer-6 partials
struct EpiF  { float4 part[32][64];   };  // 32 KB fwd layer-6 partials
union  ShU   { MainS m; EpiP ep; EpiF ef; };

struct SmallS {
  float2 xpt[32];
  float  fin[8][20];
  float  red[32];
  float  redB[32];
};

// ---------------- PDE body: 8 points/block, 5 coupled streams ----------------
// wave w: points 2w,2w+1; lane owns cols 4*lane..4*lane+3; X in registers,
// k-broadcast via v_readlane (k = 4*srclane + slot). Zero shuffles.
__device__ __forceinline__ void pde_body(const KP& P, ShU& U, SmallS& SS, int bid){
  const int tid = threadIdx.x;
  const int g0  = bid * 8;
  if (tid < 8){ int g = g0 + tid; SS.xpt[tid] = make_float2(P.f1[2*g], P.f1[2*g+1]); }
  __syncthreads();

  const int lane = tid & 63;
  const int c0   = lane * 4;
  const int p0   = (tid >> 6) * 2;

  float xr[2][5][4];   // [pt][stream][slot]: lane's cols = next layer's k=4*lane+slot

  // ---- layer 0 ----
  {
    float4 w0 = *(const float4*)(P.W0 + c0);
    float4 w1 = *(const float4*)(P.W0 + 256 + c0);
    float4 b0 = *(const float4*)(P.b0 + c0);
    const float wz[4] = {w0.x,w0.y,w0.z,w0.w};
    const float wr[4] = {w1.x,w1.y,w1.z,w1.w};
    const float bb[4] = {b0.x,b0.y,b0.z,b0.w};
    #pragma unroll
    for (int pp=0;pp<2;++pp){
      float x0 = SS.xpt[p0+pp].x, x1 = SS.xpt[p0+pp].y;
      #pragma unroll
      for (int c=0;c<4;++c){
        float a = x0*wz[c] + x1*wr[c] + bb[c];
        float t = ftanh(a), s = 1.f - t*t, cc = -2.f*t*s;
        xr[pp][0][c]=t; xr[pp][1][c]=s*wz[c]; xr[pp][2][c]=s*wr[c];
        xr[pp][3][c]=cc*wz[c]*wz[c]; xr[pp][4][c]=cc*wr[c]*wr[c];
      }
    }
  }

  // ---- layers 1..5 ----
  const float* Wl[5] = {P.W1,P.W2,P.W3,P.W4,P.W5};
  const float* bl[5] = {P.b1,P.b2,P.b3,P.b4,P.b5};
  for (int l=0;l<5;++l){
    const float* Wg = Wl[l];
    float acc[2][5][4];
    #pragma unroll
    for (int pp=0;pp<2;++pp)
      #pragma unroll
      for (int s=0;s<5;++s)
        #pragma unroll
        for (int c=0;c<4;++c) acc[pp][s][c] = 0.f;

    float4 ra = ((const float4*)Wg)[tid];
    float4 rb = ((const float4*)Wg)[tid+256];
    for (int kt=0; kt<32; ++kt){
      const int buf = kt & 1;
      { float4* dst = (float4*)(&U.m.Wt[buf][0][0]); dst[tid]=ra; dst[tid+256]=rb; }
      if (kt < 31){
        const float4* src = (const float4*)(Wg + (kt+1)*2048);
        ra = src[tid]; rb = src[tid+256];
      }
      __syncthreads();
      #pragma unroll
      for (int kk=0;kk<8;++kk){
        float4 wv = *(const float4*)&U.m.Wt[buf][kk][c0];
        const int srcl = kt*2 + (kk>>2);
        #pragma unroll
        for (int pp=0;pp<2;++pp)
          #pragma unroll
          for (int s=0;s<5;++s){
            float xs = rl(xr[pp][s][kk&3], srcl);
            acc[pp][s][0] += xs*wv.x; acc[pp][s][1] += xs*wv.y;
            acc[pp][s][2] += xs*wv.z; acc[pp][s][3] += xs*wv.w;
          }
      }
    }
    float4 bvl = *(const float4*)(bl[l] + c0);
    const float bb[4] = {bvl.x,bvl.y,bvl.z,bvl.w};
    #pragma unroll
    for (int pp=0;pp<2;++pp)
      #pragma unroll
      for (int c=0;c<4;++c){
        float a   = acc[pp][0][c] + bb[c];
        float Dz  = acc[pp][1][c], Dr = acc[pp][2][c];
        float Dzz = acc[pp][3][c], Drr = acc[pp][4][c];
        float t = ftanh(a), s = 1.f - t*t, cc = -2.f*t*s;
        xr[pp][0][c]=t; xr[pp][1][c]=s*Dz; xr[pp][2][c]=s*Dr;
        xr[pp][3][c]=s*Dzz + cc*Dz*Dz; xr[pp][4][c]=s*Drr + cc*Dr*Dr;
      }
  }

  // ---- layer 6: fold W6 per-lane, float4 partial -> LDS -> 40-thread finish ----
  __syncthreads();   // all waves done with Wt before union reuse
  {
    float4 w6r[4];
    #pragma unroll
    for (int slot=0;slot<4;++slot) w6r[slot] = *(const float4*)(P.W6 + (c0+slot)*4);
    #pragma unroll
    for (int pp=0;pp<2;++pp)
      #pragma unroll
      for (int s=0;s<5;++s){
        float4 a4 = make_float4(0.f,0.f,0.f,0.f);
        #pragma unroll
        for (int slot=0;slot<4;++slot){
          float x = xr[pp][s][slot];
          a4.x += x*w6r[slot].x; a4.y += x*w6r[slot].y;
          a4.z += x*w6r[slot].z; a4.w += x*w6r[slot].w;
        }
        U.ep.part[p0+pp][s][lane] = a4;
      }
  }
  __syncthreads();
  if (tid < 40){
    const int pt = tid / 5, s = tid - pt*5;
    float sx=0.f, sy=0.f, sz=0.f, sw=0.f;
    for (int i=0;i<64;++i){
      int ll = (tid + i) & 63;          // stagger -> spread banks
      float4 v = U.ep.part[pt][s][ll];
      sx += v.x; sy += v.y; sz += v.z; sw += v.w;
    }
    if (s == 0){ sx += P.b6[0]; sy += P.b6[1]; sz += P.b6[2]; sw += P.b6[3]; }
    SS.fin[pt][4*s+0] = sx; SS.fin[pt][4*s+1] = sy;
    SS.fin[pt][4*s+2] = sz; SS.fin[pt][4*s+3] = sw;
  }
  __syncthreads();
  if (tid < 8){
    const float* F = SS.fin[tid];
    float r = SS.xpt[tid].y;
    float uz=F[0],  us=F[1],  ur=F[2];
    float uz_z=F[4],us_z=F[5],ur_z=F[6],p_z=F[7];
    float uz_r=F[8],us_r=F[9],ur_r=F[10],p_r=F[11];
    float uz_zz=F[12],us_zz=F[13],ur_zz=F[14];
    float uz_rr=F[16],us_rr=F[17],ur_rr=F[18];
    float invr = 1.f/r;
    float eq1 = ur*ur_r + uz*ur_z - us*us*invr + p_r
              - NUC*invr*ur_r - NUC*ur_rr - NUC*ur_zz + NUC*ur*invr*invr;
    float eq2 = ur*us_r + uz*us_z + ur*us*invr
              - NUC*invr*us_r - NUC*us_rr - NUC*us_zz + NUC*us*invr*invr;
    float eq3 = ur*uz_r + uz*uz_z + p_z
              - NUC*invr*uz_r - NUC*uz_rr - NUC*uz_zz;
    float eq4 = ur + r*ur_r + r*uz_z;
    SS.red[tid] = (eq1*eq1 + eq2*eq2 + eq3*eq3 + eq4*eq4) * (1.0f/80000.f);
  }
  __syncthreads();
  if (tid == 0){
    float sum = 0.f;
    #pragma unroll
    for (int i=0;i<8;++i) sum += SS.red[i];
    P.wsF[bid] = sum;
  }
}

// ---------------- forward-only body: 32 points/block ----------------
__device__ __forceinline__ void fwd_body(const KP& P, ShU& U, SmallS& SS, int bid){
  const int tid = threadIdx.x;
  const int g0  = bid * 32;
  if (tid < 32){
    int g = g0 + tid;
    float2 xy = make_float2(0.f,0.f);
    if (g < 37000){
      const float* src; int li;
      if      (g <  1000){ src=P.bc1; li=g; }
      else if (g <  2000){ src=P.bc2; li=g-1000; }
      else if (g <  7000){ src=P.bc3; li=g-2000; }
      else if (g < 12000){ src=P.bc4; li=g-7000; }
      else if (g < 17000){ src=P.bc5; li=g-12000; }
      else               { src=P.inp; li=g-17000; }
      xy.x = src[2*li]; xy.y = src[2*li+1];
    }
    SS.xpt[tid] = xy;
  }
  __syncthreads();

  const int lane = tid & 63;
  const int c0   = lane * 4;
  const int p0   = (tid >> 6) * 8;

  float xr[8][4];
  {
    float4 w0 = *(const float4*)(P.W0 + c0);
    float4 w1 = *(const float4*)(P.W0 + 256 + c0);
    float4 b0 = *(const float4*)(P.b0 + c0);
    const float wz[4] = {w0.x,w0.y,w0.z,w0.w};
    const float wr[4] = {w1.x,w1.y,w1.z,w1.w};
    const float bb[4] = {b0.x,b0.y,b0.z,b0.w};
    #pragma unroll
    for (int i=0;i<8;++i){
      float x0 = SS.xpt[p0+i].x, x1 = SS.xpt[p0+i].y;
      #pragma unroll
      for (int c=0;c<4;++c)
        xr[i][c] = ftanh(x0*wz[c] + x1*wr[c] + bb[c]);
    }
  }

  const float* Wl[5] = {P.W1,P.W2,P.W3,P.W4,P.W5};
  const float* bl[5] = {P.b1,P.b2,P.b3,P.b4,P.b5};
  for (int l=0;l<5;++l){
    const float* Wg = Wl[l];
    float acc[8][4];
    #pragma unroll
    for (int i=0;i<8;++i){ acc[i][0]=0.f; acc[i][1]=0.f; acc[i][2]=0.f; acc[i][3]=0.f; }

    float4 ra = ((const float4*)Wg)[tid];
    float4 rb = ((const float4*)Wg)[tid+256];
    for (int kt=0; kt<32; ++kt){
      const int buf = kt & 1;
      { float4* dst = (float4*)(&U.m.Wt[buf][0][0]); dst[tid]=ra; dst[tid+256]=rb; }
      if (kt < 31){
        const float4* src = (const float4*)(Wg + (kt+1)*2048);
        ra = src[tid]; rb = src[tid+256];
      }
      __syncthreads();
      #pragma unroll
      for (int kk=0;kk<8;++kk){
        float4 wv = *(const float4*)&U.m.Wt[buf][kk][c0];
        const int srcl = kt*2 + (kk>>2);
        #pragma unroll
        for (int i=0;i<8;++i){
          float xs = rl(xr[i][kk&3], srcl);
          acc[i][0] += xs*wv.x; acc[i][1] += xs*wv.y;
          acc[i][2] += xs*wv.z; acc[i][3] += xs*wv.w;
        }
      }
    }
    float4 bvl = *(const float4*)(bl[l] + c0);
    const float bb[4] = {bvl.x,bvl.y,bvl.z,bvl.w};
    #pragma unroll
    for (int i=0;i<8;++i)
      #pragma unroll
      for (int c=0;c<4;++c)
        xr[i][c] = ftanh(acc[i][c] + bb[c]);
  }

  // ---- layer 6 + per-point MSE (LDS partials, no shuffles) ----
  __syncthreads();   // union reuse
  {
    float4 w6r[4];
    #pragma unroll
    for (int slot=0;slot<4;++slot) w6r[slot] = *(const float4*)(P.W6 + (c0+slot)*4);
    #pragma unroll
    for (int i=0;i<8;++i){
      float4 a4 = make_float4(0.f,0.f,0.f,0.f);
      #pragma unroll
      for (int slot=0;slot<4;++slot){
        float x = xr[i][slot];
        a4.x += x*w6r[slot].x; a4.y += x*w6r[slot].y;
        a4.z += x*w6r[slot].z; a4.w += x*w6r[slot].w;
      }
      U.ef.part[p0+i][lane] = a4;
    }
  }
  __syncthreads();
  if (tid < 32){
    const int pt = tid;
    float sx=0.f, sy=0.f, sz=0.f, sw=0.f;
    for (int i=0;i<64;++i){
      int ll = (pt + i) & 63;
      float4 v = U.ef.part[pt][ll];
      sx += v.x; sy += v.y; sz += v.z; sw += v.w;
    }
    float dj0 = sx + P.b6[0], dj1 = sy + P.b6[1];
    float dj2 = sz + P.b6[2], dj3 = sw + P.b6[3];
    float bcp = 0.f, dap = 0.f;
    int g = g0 + pt;
    if (g < 37000){
      if      (g <  2000){ bcp = (dj0*dj0 + dj1*dj1 + dj2*dj2)*(1.0f/1000.f); }
      else if (g <  7000){ float d1 = dj1 - 1.f;
                           bcp = (dj0*dj0 + d1*d1 + dj2*dj2)*(1.0f/5000.f); }
      else if (g < 12000){ bcp = (dj0*dj0 + dj1*dj1 + dj2*dj2)*(1.0f/5000.f); }
      else if (g < 17000){ bcp = dj3*dj3*(1.0f/5000.f); }
      else { const float* rr = P.real + (g-17000)*4;
             float e0=dj0-rr[0], e1=dj1-rr[1], e2=dj2-rr[2], e3=dj3-rr[3];
             dap = (e0*e0 + e1*e1 + e2*e2 + e3*e3)*(1.0f/80000.f); }
    }
    SS.red[pt] = bcp; SS.redB[pt] = dap;
  }
  __syncthreads();
  if (tid == 0){
    float sA=0.f, sB=0.f;
    #pragma unroll
    for (int i=0;i<32;++i){ sA += SS.red[i]; sB += SS.redB[i]; }
    P.wsBC[bid] = sA; P.wsDA[bid] = sB;
  }
}

// ---------------- fused kernel: pde blocks first (longer), then fwd ----------------
__global__ __launch_bounds__(256,3) void fused_kernel(KP P, int nbP){
  __shared__ ShU U;
  __shared__ SmallS SS;
  if ((int)blockIdx.x < nbP) pde_body(P, U, SS, blockIdx.x);
  else                       fwd_body(P, U, SS, blockIdx.x - nbP);
}

// ---------------- final deterministic reduction ----------------
__global__ void reduce_kernel(const float* wsBC, const float* wsDA, const float* wsF,
                              float* out, int nbF, int nbP){
  __shared__ float sm[256];
  const int tid = threadIdx.x;
  float a;

  a = 0.f; for (int i=tid;i<nbF;i+=256) a += wsBC[i];
  sm[tid]=a; __syncthreads();
  for (int off=128; off>0; off>>=1){ if (tid<off) sm[tid]+=sm[tid+off]; __syncthreads(); }
  if (tid==0) out[0]=sm[0];
  __syncthreads();

  a = 0.f; for (int i=tid;i<nbF;i+=256) a += wsDA[i];
  sm[tid]=a; __syncthreads();
  for (int off=128; off>0; off>>=1){ if (tid<off) sm[tid]+=sm[tid+off]; __syncthreads(); }
  if (tid==0) out[1]=sm[0];
  __syncthreads();

  a = 0.f; for (int i=tid;i<nbP;i+=256) a += wsF[i];
  sm[tid]=a; __syncthreads();
  for (int off=128; off>0; off>>=1){ if (tid<off) sm[tid]+=sm[tid+off]; __syncthreads(); }
  if (tid==0) out[2]=sm[0];
}

extern "C" void kernel_launch(void* const* d_in, const int* in_sizes, int n_in,
                              void* d_out, int out_size, void* d_ws, size_t ws_size,
                              hipStream_t stream){
  KP P;
  P.W0=(const float*)d_in[0];  P.b0=(const float*)d_in[1];
  P.W1=(const float*)d_in[2];  P.b1=(const float*)d_in[3];
  P.W2=(const float*)d_in[4];  P.b2=(const float*)d_in[5];
  P.W3=(const float*)d_in[6];  P.b3=(const float*)d_in[7];
  P.W4=(const float*)d_in[8];  P.b4=(const float*)d_in[9];
  P.W5=(const float*)d_in[10]; P.b5=(const float*)d_in[11];
  P.W6=(const float*)d_in[12]; P.b6=(const float*)d_in[13];
  P.bc1=(const float*)d_in[14]; P.bc2=(const float*)d_in[15];
  P.bc3=(const float*)d_in[16]; P.bc4=(const float*)d_in[17];
  P.bc5=(const float*)d_in[18]; P.f1=(const float*)d_in[19];
  P.inp=(const float*)d_in[20]; P.real=(const float*)d_in[21];
  float* ws = (float*)d_ws;
  P.wsBC = ws; P.wsDA = ws + 2048; P.wsF = ws + 4096;

  const int nbF = (37000 + 31) / 32;   // 1157
  const int nbP = 20000 / 8;           // 2500
  fused_kernel<<<dim3(nbP + nbF), dim3(256), 0, stream>>>(P, nbP);
  reduce_kernel<<<dim3(1), dim3(256), 0, stream>>>(P.wsBC, P.wsDA, P.wsF, (float*)d_out, nbF, nbP);
}

// Round 5
// 344.780 us; speedup vs baseline: 4.0609x; 3.9597x over previous
//
#include <hip/hip_runtime.h>

#define NUC 8.0e-4f   // MIU/(U*L)

typedef __attribute__((ext_vector_type(8))) short   bf16x8;
typedef __attribute__((ext_vector_type(8))) unsigned short u16x8;
typedef __attribute__((ext_vector_type(4))) float   f32x4;

struct KP {
  const float *W0,*b0,*W1,*b1,*W2,*b2,*W3,*b3,*W4,*b4,*W5,*b5,*W6,*b6;
  const float *bc1,*bc2,*bc3,*bc4,*bc5,*f1,*inp,*real;
  const unsigned short *Wfh,*Wfl;   // frag-ordered bf16 hi/lo for W1..W5
  float *wsBC,*wsDA,*wsF;
};

__device__ __forceinline__ float ftanh(float a){
  float e = __expf(2.0f*a);
  return 1.0f - 2.0f/(e + 1.0f);
}
__device__ __forceinline__ void splitf(float v, unsigned short& h, unsigned short& l){
  unsigned int b = __float_as_uint(v);
  h = (unsigned short)(b >> 16);
  float lo = v - __uint_as_float(b & 0xFFFF0000u);
  l = (unsigned short)(__float_as_uint(lo) >> 16);
}
// A term-array byte addr (bf16 [80][256], row stride 512B) with bank swizzle
__device__ __forceinline__ int aswz(int row, int kbyte){
  return (row*512 + kbyte) ^ ((row & 7) << 4);
}
// final-layer f32 A6 [80][256]
__device__ __forceinline__ int a6swz(int row, int col){
  return (row*1024 + col*4) ^ ((row & 7) << 4);
}

// ---------------- prep: split W1..W5 into frag-ordered bf16 hi/lo ----------------
// frag order: [layer][ks(8)][ntile(16)][lane(64)][e(8)]; lane = ((k&31)>>3)*16 + (col&15), e = k&7
__global__ void prep_kernel(const float* W1, const float* W2, const float* W3,
                            const float* W4, const float* W5,
                            unsigned short* Wfh, unsigned short* Wfl){
  int idx = blockIdx.x*256 + threadIdx.x;      // 0..327679 (5*65536)
  int li  = idx >> 16;
  int rem = idx & 65535;
  int k   = rem >> 8;
  int col = rem & 255;
  const float* Ws[5] = {W1,W2,W3,W4,W5};
  float v = Ws[li][k*256 + col];
  unsigned short hi, lo;
  splitf(v, hi, lo);
  int ks = k >> 5, kr = k & 31, q = kr >> 3, e = kr & 7;
  int lane = q*16 + (col & 15), nt = col >> 4;
  int pos = li*65536 + (ks*16 + nt)*512 + lane*8 + e;
  Wfh[pos] = hi; Wfl[pos] = lo;
}

struct LDSm {
  unsigned char Abuf[81920];   // hi bf16 [80][256] @0, lo @40960; or f32 A6 [80][256]
  float2 xpt[80];
  float  fin[320];             // pde: [16][20]; fwd: [80][4]
  float  red[80];
  float  redB[80];
};

// ---------------- fused main kernel: 512 thr, M=80, N=256, MFMA 16x16x32 bf16 ----------------
__global__ __launch_bounds__(512,2) void fused_kernel(KP P, int nbP){
  __shared__ LDSm L;
  const int tid  = threadIdx.x;
  const int lane = tid & 63;
  const int wv   = tid >> 6;          // 0..7
  const bool isP = (int)blockIdx.x < nbP;
  const int bid  = isP ? (int)blockIdx.x : (int)blockIdx.x - nbP;

  // ---- point coords ----
  if (isP){
    if (tid < 16){ int g = bid*16 + tid; L.xpt[tid] = make_float2(P.f1[2*g], P.f1[2*g+1]); }
  } else {
    if (tid < 80){
      int g = bid*80 + tid;
      float2 xy = make_float2(0.f,0.f);
      if (g < 37000){
        const float* src; int li2;
        if      (g <  1000){ src=P.bc1; li2=g; }
        else if (g <  2000){ src=P.bc2; li2=g-1000; }
        else if (g <  7000){ src=P.bc3; li2=g-2000; }
        else if (g < 12000){ src=P.bc4; li2=g-7000; }
        else if (g < 17000){ src=P.bc5; li2=g-12000; }
        else               { src=P.inp; li2=g-17000; }
        xy.x = src[2*li2]; xy.y = src[2*li2+1];
      }
      L.xpt[tid] = xy;
    }
  }
  __syncthreads();

  // ---- layer 0 (2 -> 256), write A hi/lo ----
  {
    const int pt = tid >> 5;      // 0..15
    const int jg = tid & 31;      // 8-col group
    const int j0 = jg*8;
    float wz[8], wr[8], bb[8];
    #pragma unroll
    for (int jj=0;jj<8;++jj){ wz[jj]=P.W0[j0+jj]; wr[jj]=P.W0[256+j0+jj]; bb[jj]=P.b0[j0+jj]; }
    if (isP){
      float x0 = L.xpt[pt].x, x1 = L.xpt[pt].y;
      u16x8 hv[5], lv[5];
      #pragma unroll
      for (int jj=0;jj<8;++jj){
        float a = x0*wz[jj] + x1*wr[jj] + bb[jj];
        float t = ftanh(a), s = 1.f - t*t, cc = -2.f*t*s;
        float o[5] = {t, s*wz[jj], s*wr[jj], cc*wz[jj]*wz[jj], cc*wr[jj]*wr[jj]};
        #pragma unroll
        for (int s_=0;s_<5;++s_){ unsigned short h_,l_; splitf(o[s_],h_,l_); hv[s_][jj]=h_; lv[s_][jj]=l_; }
      }
      #pragma unroll
      for (int s_=0;s_<5;++s_){
        int byte = aswz(s_*16 + pt, jg*16);
        *(u16x8*)(L.Abuf + byte)         = hv[s_];
        *(u16x8*)(L.Abuf + 40960 + byte) = lv[s_];
      }
    } else {
      #pragma unroll
      for (int pp=0;pp<5;++pp){
        int row = pt + 16*pp;
        float x0 = L.xpt[row].x, x1 = L.xpt[row].y;
        u16x8 hv, lv;
        #pragma unroll
        for (int jj=0;jj<8;++jj){
          float t = ftanh(x0*wz[jj] + x1*wr[jj] + bb[jj]);
          unsigned short h_,l_; splitf(t,h_,l_); hv[jj]=h_; lv[jj]=l_;
        }
        int byte = aswz(row, jg*16);
        *(u16x8*)(L.Abuf + byte)         = hv;
        *(u16x8*)(L.Abuf + 40960 + byte) = lv;
      }
    }
  }

  // ---- layers 1..5: C = A_hi*W_hi + A_hi*W_lo + A_lo*W_hi, pointwise lane-local ----
  const int q    = lane >> 4;     // 0..3
  const int lrow = lane & 15;
  #pragma unroll
  for (int li=0; li<5; ++li){
    const float* bl = (li==0)?P.b1:(li==1)?P.b2:(li==2)?P.b3:(li==3)?P.b4:P.b5;
    const unsigned short* WH = P.Wfh + li*65536;
    const unsigned short* WL = P.Wfl + li*65536;
    f32x4 acc[5][2];
    #pragma unroll
    for (int m=0;m<5;++m)
      #pragma unroll
      for (int n=0;n<2;++n){ acc[m][n][0]=0.f; acc[m][n][1]=0.f; acc[m][n][2]=0.f; acc[m][n][3]=0.f; }
    __syncthreads();   // A' of previous layer visible
    for (int ks=0; ks<8; ++ks){
      bf16x8 bh[2], bo[2], ah[5], al[5];
      #pragma unroll
      for (int n=0;n<2;++n){
        int idx = (ks*16 + (wv*2+n))*512 + lane*8;
        bh[n] = *(const bf16x8*)(WH + idx);
        bo[n] = *(const bf16x8*)(WL + idx);
      }
      #pragma unroll
      for (int m=0;m<5;++m){
        int byte = aswz(m*16 + lrow, ks*64 + q*16);
        ah[m] = *(const bf16x8*)(L.Abuf + byte);
        al[m] = *(const bf16x8*)(L.Abuf + 40960 + byte);
      }
      #pragma unroll
      for (int m=0;m<5;++m)
        #pragma unroll
        for (int n=0;n<2;++n){
          acc[m][n] = __builtin_amdgcn_mfma_f32_16x16x32_bf16(ah[m], bh[n], acc[m][n], 0,0,0);
          acc[m][n] = __builtin_amdgcn_mfma_f32_16x16x32_bf16(ah[m], bo[n], acc[m][n], 0,0,0);
          acc[m][n] = __builtin_amdgcn_mfma_f32_16x16x32_bf16(al[m], bh[n], acc[m][n], 0,0,0);
        }
    }
    __syncthreads();   // all A reads done before overwrite
    #pragma unroll
    for (int n=0;n<2;++n){
      int col = (wv*2+n)*16 + lrow;
      float bias = bl[col];
      #pragma unroll
      for (int r=0;r<4;++r){
        int rw = q*4 + r;
        if (isP){
          float a  = acc[0][n][r] + bias;
          float Dz = acc[1][n][r], Dr = acc[2][n][r];
          float Dzz= acc[3][n][r], Drr= acc[4][n][r];
          float t = ftanh(a), s = 1.f - t*t, cc = -2.f*t*s;
          float o[5] = {t, s*Dz, s*Dr, s*Dzz + cc*Dz*Dz, s*Drr + cc*Dr*Dr};
          #pragma unroll
          for (int s_=0;s_<5;++s_){
            int row = s_*16 + rw;
            if (li < 4){
              unsigned short h_,l_; splitf(o[s_],h_,l_);
              *(unsigned short*)(L.Abuf + aswz(row, col*2)) = h_;
              *(unsigned short*)(L.Abuf + 40960 + aswz(row, col*2)) = l_;
            } else {
              *(float*)(L.Abuf + a6swz(row, col)) = o[s_];
            }
          }
        } else {
          #pragma unroll
          for (int m=0;m<5;++m){
            int row = m*16 + rw;
            float t = ftanh(acc[m][n][r] + bias);
            if (li < 4){
              unsigned short h_,l_; splitf(t,h_,l_);
              *(unsigned short*)(L.Abuf + aswz(row, col*2)) = h_;
              *(unsigned short*)(L.Abuf + 40960 + aswz(row, col*2)) = l_;
            } else {
              *(float*)(L.Abuf + a6swz(row, col)) = t;
            }
          }
        }
      }
    }
  }
  __syncthreads();

  // ---- layer 6 (256 -> 4), f32 ----
  if (tid < 320){
    int row = tid >> 2, jo = tid & 3;
    float dot = 0.f;
    int k0 = (row*8) & 255;
    for (int it=0; it<256; ++it){
      int k = (k0 + it) & 255;
      dot += *(const float*)(L.Abuf + a6swz(row, k)) * P.W6[k*4 + jo];
    }
    if (isP){
      int s_ = row >> 4, pt = row & 15;
      if (s_ == 0) dot += P.b6[jo];
      L.fin[pt*20 + s_*4 + jo] = dot;
    } else {
      dot += P.b6[jo];
      L.fin[row*4 + jo] = dot;
    }
  }
  __syncthreads();

  // ---- loss terms ----
  if (isP){
    if (tid < 16){
      const float* F = &L.fin[tid*20];
      float r = L.xpt[tid].y;
      float uz=F[0],  us=F[1],  ur=F[2];
      float uz_z=F[4],us_z=F[5],ur_z=F[6],p_z=F[7];
      float uz_r=F[8],us_r=F[9],ur_r=F[10],p_r=F[11];
      float uz_zz=F[12],us_zz=F[13],ur_zz=F[14];
      float uz_rr=F[16],us_rr=F[17],ur_rr=F[18];
      float invr = 1.f/r;
      float eq1 = ur*ur_r + uz*ur_z - us*us*invr + p_r
                - NUC*invr*ur_r - NUC*ur_rr - NUC*ur_zz + NUC*ur*invr*invr;
      float eq2 = ur*us_r + uz*us_z + ur*us*invr
                - NUC*invr*us_r - NUC*us_rr - NUC*us_zz + NUC*us*invr*invr;
      float eq3 = ur*uz_r + uz*uz_z + p_z
                - NUC*invr*uz_r - NUC*uz_rr - NUC*uz_zz;
      float eq4 = ur + r*ur_r + r*uz_z;
      L.red[tid] = (eq1*eq1 + eq2*eq2 + eq3*eq3 + eq4*eq4) * (1.0f/80000.f);
    }
    __syncthreads();
    if (tid == 0){
      float s = 0.f;
      #pragma unroll
      for (int i=0;i<16;++i) s += L.red[i];
      P.wsF[bid] = s;
    }
  } else {
    if (tid < 80){
      float dj0 = L.fin[tid*4+0], dj1 = L.fin[tid*4+1];
      float dj2 = L.fin[tid*4+2], dj3 = L.fin[tid*4+3];
      float bcp = 0.f, dap = 0.f;
      int g = bid*80 + tid;
      if (g < 37000){
        if      (g <  2000){ bcp = (dj0*dj0 + dj1*dj1 + dj2*dj2)*(1.0f/1000.f); }
        else if (g <  7000){ float d1 = dj1 - 1.f;
                             bcp = (dj0*dj0 + d1*d1 + dj2*dj2)*(1.0f/5000.f); }
        else if (g < 12000){ bcp = (dj0*dj0 + dj1*dj1 + dj2*dj2)*(1.0f/5000.f); }
        else if (g < 17000){ bcp = dj3*dj3*(1.0f/5000.f); }
        else { const float* rr = P.real + (g-17000)*4;
               float e0=dj0-rr[0], e1=dj1-rr[1], e2=dj2-rr[2], e3=dj3-rr[3];
               dap = (e0*e0 + e1*e1 + e2*e2 + e3*e3)*(1.0f/80000.f); }
      }
      L.red[tid] = bcp; L.redB[tid] = dap;
    }
    __syncthreads();
    if (tid == 0){
      float sA=0.f, sB=0.f;
      #pragma unroll
      for (int i=0;i<80;++i){ sA += L.red[i]; sB += L.redB[i]; }
      P.wsBC[bid] = sA; P.wsDA[bid] = sB;
    }
  }
}

// ---------------- final deterministic reduction ----------------
__global__ void reduce_kernel(const float* wsBC, const float* wsDA, const float* wsF,
                              float* out, int nbBC, int nbP){
  __shared__ float sm[256];
  const int tid = threadIdx.x;
  float a;

  a = 0.f; for (int i=tid;i<nbBC;i+=256) a += wsBC[i];
  sm[tid]=a; __syncthreads();
  for (int off=128; off>0; off>>=1){ if (tid<off) sm[tid]+=sm[tid+off]; __syncthreads(); }
  if (tid==0) out[0]=sm[0];
  __syncthreads();

  a = 0.f; for (int i=tid;i<nbBC;i+=256) a += wsDA[i];
  sm[tid]=a; __syncthreads();
  for (int off=128; off>0; off>>=1){ if (tid<off) sm[tid]+=sm[tid+off]; __syncthreads(); }
  if (tid==0) out[1]=sm[0];
  __syncthreads();

  a = 0.f; for (int i=tid;i<nbP;i+=256) a += wsF[i];
  sm[tid]=a; __syncthreads();
  for (int off=128; off>0; off>>=1){ if (tid<off) sm[tid]+=sm[tid+off]; __syncthreads(); }
  if (tid==0) out[2]=sm[0];
}

extern "C" void kernel_launch(void* const* d_in, const int* in_sizes, int n_in,
                              void* d_out, int out_size, void* d_ws, size_t ws_size,
                              hipStream_t stream){
  KP P;
  P.W0=(const float*)d_in[0];  P.b0=(const float*)d_in[1];
  P.W1=(const float*)d_in[2];  P.b1=(const float*)d_in[3];
  P.W2=(const float*)d_in[4];  P.b2=(const float*)d_in[5];
  P.W3=(const float*)d_in[6];  P.b3=(const float*)d_in[7];
  P.W4=(const float*)d_in[8];  P.b4=(const float*)d_in[9];
  P.W5=(const float*)d_in[10]; P.b5=(const float*)d_in[11];
  P.W6=(const float*)d_in[12]; P.b6=(const float*)d_in[13];
  P.bc1=(const float*)d_in[14]; P.bc2=(const float*)d_in[15];
  P.bc3=(const float*)d_in[16]; P.bc4=(const float*)d_in[17];
  P.bc5=(const float*)d_in[18]; P.f1=(const float*)d_in[19];
  P.inp=(const float*)d_in[20]; P.real=(const float*)d_in[21];

  unsigned short* wf = (unsigned short*)d_ws;
  P.Wfh = wf;                 // 327680 ushort
  P.Wfl = wf + 327680;        // 327680 ushort
  float* pb = (float*)((char*)d_ws + 1310720);
  P.wsBC = pb; P.wsDA = pb + 512; P.wsF = pb + 1024;   // 463,463,1250 used

  const int nbP  = 20000 / 16;           // 1250 pde blocks (16 pts each)
  const int nbBC = (37000 + 79) / 80;    // 463 fwd blocks (80 pts each)

  prep_kernel<<<dim3(1280), dim3(256), 0, stream>>>(
      P.W1, P.W2, P.W3, P.W4, P.W5,
      (unsigned short*)wf, (unsigned short*)(wf + 327680));
  fused_kernel<<<dim3(nbP + nbBC), dim3(512), 0, stream>>>(P, nbP);
  reduce_kernel<<<dim3(1), dim3(256), 0, stream>>>(P.wsBC, P.wsDA, P.wsF,
                                                   (float*)d_out, nbBC, nbP);
}